// Round 4
// baseline (18.530 us; speedup 1.0000x reference)
//
#include <hip/hip_runtime.h>

// Fused LSTM(1 step, in=1, hidden=2) + ReLU + FC(2->128)+ReLU + FC(128->5).
//
// When h==0 && c==0 (the provided inputs) and XLO<x<XHI, output = F(x), a
// smooth scalar function. Kernel 1 tabulates F on a 2048-interval grid over
// [-6,6] (lerp err ~3e-5 << 9.4e-3 threshold) with 16 lanes/entry + shfl
// reduce. Kernel 2 stages the 41 KB table into LDS per block, then each
// thread processes 4 samples: check h/c==0, lerp from LDS, float4 I/O.
// Any sample with nonzero h/c or out-of-range x takes the exact full path,
// so the kernel is correct for arbitrary inputs.

#define FC1 128
#define NT 2048
#define XLO (-6.0f)
#define XHI (6.0f)
#define SCALE ((float)NT / (XHI - XLO))

__device__ float4 g_A[NT + 1];   // {a0,a1,a2,a3} per entry
__device__ float  g_D[NT + 1];   // a4 per entry

__device__ __forceinline__ float sigmoid_f(float x) {
    return 1.0f / (1.0f + __expf(-x));
}
__device__ __forceinline__ float tanh_f(float x) {
    return 1.0f - 2.0f / (__expf(2.0f * x) + 1.0f);
}

// LSTM cell -> relu(h) for one sample.
__device__ __forceinline__ void lstm_part(
    float xv, float h0v, float h1v, float c0v, float c1v,
    const float* __restrict__ W_ih, const float* __restrict__ W_hh,
    const float* __restrict__ b_ih, const float* __restrict__ b_hh,
    float& hx, float& hy)
{
    float gp[8];
#pragma unroll
    for (int j = 0; j < 8; ++j) {
        gp[j] = fmaf(W_ih[j], xv,
                 fmaf(W_hh[2*j], h0v,
                  fmaf(W_hh[2*j+1], h1v, b_ih[j] + b_hh[j])));
    }
    float i0 = sigmoid_f(gp[0]), i1 = sigmoid_f(gp[1]);
    float f0 = sigmoid_f(gp[2]), f1 = sigmoid_f(gp[3]);
    float g0 = tanh_f(gp[4]),    g1 = tanh_f(gp[5]);
    float o0 = sigmoid_f(gp[6]), o1 = sigmoid_f(gp[7]);
    float cn0 = fmaf(f0, c0v, i0 * g0);
    float cn1 = fmaf(f1, c1v, i1 * g1);
    hx = fmaxf(o0 * tanh_f(cn0), 0.0f);
    hy = fmaxf(o1 * tanh_f(cn1), 0.0f);
}

// Exact model evaluation (fallback path, rarely taken).
__device__ void full_eval(
    float xv, float h0v, float h1v, float c0v, float c1v,
    const float* __restrict__ W_ih, const float* __restrict__ W_hh,
    const float* __restrict__ b_ih, const float* __restrict__ b_hh,
    const float* __restrict__ W1,   const float* __restrict__ b1,
    const float* __restrict__ W2,   const float* __restrict__ b2,
    float* a)
{
    float hx, hy;
    lstm_part(xv, h0v, h1v, c0v, c1v, W_ih, W_hh, b_ih, b_hh, hx, hy);
    float a0 = b2[0], a1 = b2[1], a2 = b2[2], a3 = b2[3], a4 = b2[4];
#pragma unroll 2
    for (int j = 0; j < FC1; ++j) {
        float u = fmaf(W1[2*j], hx, fmaf(W1[2*j+1], hy, b1[j]));
        u = fmaxf(u, 0.0f);
        a0 = fmaf(W2[0*FC1 + j], u, a0);
        a1 = fmaf(W2[1*FC1 + j], u, a1);
        a2 = fmaf(W2[2*FC1 + j], u, a2);
        a3 = fmaf(W2[3*FC1 + j], u, a3);
        a4 = fmaf(W2[4*FC1 + j], u, a4);
    }
    a[0] = a0; a[1] = a1; a[2] = a2; a[3] = a3; a[4] = a4;
}

// LUT build: 16 lanes per entry, 8 FC1 neurons each, shfl-xor reduce.
__global__ __launch_bounds__(256) void build_lut_kernel(
    const float* __restrict__ W_ih, const float* __restrict__ W_hh,
    const float* __restrict__ b_ih, const float* __restrict__ b_hh,
    const float* __restrict__ W1,   const float* __restrict__ b1,
    const float* __restrict__ W2,   const float* __restrict__ b2)
{
    int tid = blockIdx.x * blockDim.x + threadIdx.x;
    int e = tid >> 4;
    int l = tid & 15;
    if (e > NT) return;

    float xv = XLO + (XHI - XLO) * ((float)e / (float)NT);
    float hx, hy;
    lstm_part(xv, 0.0f, 0.0f, 0.0f, 0.0f, W_ih, W_hh, b_ih, b_hh, hx, hy);

    float a0 = 0.f, a1 = 0.f, a2 = 0.f, a3 = 0.f, a4 = 0.f;
    int j0 = l * 8;
#pragma unroll
    for (int jj = 0; jj < 8; ++jj) {
        int j = j0 + jj;
        float u = fmaf(W1[2*j], hx, fmaf(W1[2*j+1], hy, b1[j]));
        u = fmaxf(u, 0.0f);
        a0 = fmaf(W2[0*FC1 + j], u, a0);
        a1 = fmaf(W2[1*FC1 + j], u, a1);
        a2 = fmaf(W2[2*FC1 + j], u, a2);
        a3 = fmaf(W2[3*FC1 + j], u, a3);
        a4 = fmaf(W2[4*FC1 + j], u, a4);
    }
#pragma unroll
    for (int m = 1; m < 16; m <<= 1) {
        a0 += __shfl_xor(a0, m);
        a1 += __shfl_xor(a1, m);
        a2 += __shfl_xor(a2, m);
        a3 += __shfl_xor(a3, m);
        a4 += __shfl_xor(a4, m);
    }
    if (l == 0) {
        g_A[e] = make_float4(a0 + b2[0], a1 + b2[1], a2 + b2[2], a3 + b2[3]);
        g_D[e] = a4 + b2[4];
    }
}

// Main: 4 samples/thread, LUT in LDS.
__global__ __launch_bounds__(256) void lstm_mlp_main(
    const float* __restrict__ x,
    const float* __restrict__ h0,
    const float* __restrict__ c0,
    const float* __restrict__ W_ih, const float* __restrict__ W_hh,
    const float* __restrict__ b_ih, const float* __restrict__ b_hh,
    const float* __restrict__ W1,   const float* __restrict__ b1,
    const float* __restrict__ W2,   const float* __restrict__ b2,
    float* __restrict__ out, int n)
{
    __shared__ float4 sA[NT + 1];
    __shared__ float  sD[NT + 1];
    int tid = threadIdx.x;
    for (int idx = tid; idx <= NT; idx += 256) {
        sA[idx] = g_A[idx];
        sD[idx] = g_D[idx];
    }
    __syncthreads();

    int i0 = (blockIdx.x * 256 + tid) * 4;
    if (i0 >= n) return;

    float4 xv = *reinterpret_cast<const float4*>(x + i0);
    float4 ha = *reinterpret_cast<const float4*>(h0 + 2 * (size_t)i0);
    float4 hb = *reinterpret_cast<const float4*>(h0 + 2 * (size_t)i0 + 4);
    float4 ca = *reinterpret_cast<const float4*>(c0 + 2 * (size_t)i0);
    float4 cb = *reinterpret_cast<const float4*>(c0 + 2 * (size_t)i0 + 4);

    float xs[4] = {xv.x, xv.y, xv.z, xv.w};
    float hs[8] = {ha.x, ha.y, ha.z, ha.w, hb.x, hb.y, hb.z, hb.w};
    float cs[8] = {ca.x, ca.y, ca.z, ca.w, cb.x, cb.y, cb.z, cb.w};
    float r[20];

#pragma unroll
    for (int s = 0; s < 4; ++s) {
        float xvs = xs[s];
        float h0v = hs[2*s], h1v = hs[2*s+1];
        float c0v = cs[2*s], c1v = cs[2*s+1];
        float* a = r + 5 * s;
        if (h0v == 0.0f && h1v == 0.0f && c0v == 0.0f && c1v == 0.0f &&
            xvs > XLO && xvs < XHI) {
            float t = (xvs - XLO) * SCALE;
            int k = (int)t;
            k = min(k, NT - 1);
            float fr = t - (float)k;
            float4 lo = sA[k];
            float4 hi = sA[k + 1];
            float dlo = sD[k];
            float dhi = sD[k + 1];
            a[0] = fmaf(fr, hi.x - lo.x, lo.x);
            a[1] = fmaf(fr, hi.y - lo.y, lo.y);
            a[2] = fmaf(fr, hi.z - lo.z, lo.z);
            a[3] = fmaf(fr, hi.w - lo.w, lo.w);
            a[4] = fmaf(fr, dhi - dlo, dlo);
        } else {
            full_eval(xvs, h0v, h1v, c0v, c1v,
                      W_ih, W_hh, b_ih, b_hh, W1, b1, W2, b2, a);
        }
    }

    float4* op = reinterpret_cast<float4*>(out + (size_t)i0 * 5);
    op[0] = make_float4(r[0],  r[1],  r[2],  r[3]);
    op[1] = make_float4(r[4],  r[5],  r[6],  r[7]);
    op[2] = make_float4(r[8],  r[9],  r[10], r[11]);
    op[3] = make_float4(r[12], r[13], r[14], r[15]);
    op[4] = make_float4(r[16], r[17], r[18], r[19]);
}

extern "C" void kernel_launch(void* const* d_in, const int* in_sizes, int n_in,
                              void* d_out, int out_size, void* d_ws, size_t ws_size,
                              hipStream_t stream) {
    const float* x    = (const float*)d_in[0];
    const float* h0   = (const float*)d_in[1];
    const float* c0   = (const float*)d_in[2];
    const float* W_ih = (const float*)d_in[3];
    const float* W_hh = (const float*)d_in[4];
    const float* b_ih = (const float*)d_in[5];
    const float* b_hh = (const float*)d_in[6];
    const float* W1   = (const float*)d_in[7];
    const float* b1   = (const float*)d_in[8];
    const float* W2   = (const float*)d_in[9];
    const float* b2   = (const float*)d_in[10];
    float* out = (float*)d_out;

    int n = in_sizes[0];  // B = 524288 (divisible by 4)

    // 1) build F(x) table: (NT+1)*16 threads
    int bt = (NT + 1) * 16;
    build_lut_kernel<<<(bt + 255) / 256, 256, 0, stream>>>(
        W_ih, W_hh, b_ih, b_hh, W1, b1, W2, b2);

    // 2) main pass: 4 samples/thread
    int threads = n / 4;
    int grid = (threads + 255) / 256;
    lstm_mlp_main<<<grid, 256, 0, stream>>>(
        x, h0, c0, W_ih, W_hh, b_ih, b_hh, W1, b1, W2, b2, out, n);
}

// Round 5
// 16.653 us; speedup vs baseline: 1.1127x; 1.1127x over previous
//
#include <hip/hip_runtime.h>

// Fused LSTM(1 step, in=1, hidden=2) + ReLU + FC(2->128)+ReLU + FC(128->5).
//
// When h==0 && c==0 (the provided inputs) and XLO<x<XHI, output = F(x), a
// smooth scalar function. Kernel 1 tabulates F on a 512-interval grid over
// [-6,6] (lerp+kink err ~5e-4 << 9.4e-3 threshold) with 32 lanes/entry +
// shfl reduce. Kernel 2 stages the 10.3 KB table into LDS (cheap: 5 MB total
// vs 20.5 MB stream), then each thread processes 4 samples with float4 I/O.
// Any sample with nonzero h/c or out-of-range x takes the exact full path,
// so the kernel is correct for arbitrary inputs.

#define FC1 128
#define NT 512
#define XLO (-6.0f)
#define XHI (6.0f)
#define SCALE ((float)NT / (XHI - XLO))

__device__ float4 g_A[NT + 1];   // {a0,a1,a2,a3} per entry
__device__ float  g_D[NT + 1];   // a4 per entry

__device__ __forceinline__ float sigmoid_f(float x) {
    return 1.0f / (1.0f + __expf(-x));
}
__device__ __forceinline__ float tanh_f(float x) {
    return 1.0f - 2.0f / (__expf(2.0f * x) + 1.0f);
}

// LSTM cell -> relu(h) for one sample.
__device__ __forceinline__ void lstm_part(
    float xv, float h0v, float h1v, float c0v, float c1v,
    const float* __restrict__ W_ih, const float* __restrict__ W_hh,
    const float* __restrict__ b_ih, const float* __restrict__ b_hh,
    float& hx, float& hy)
{
    float gp[8];
#pragma unroll
    for (int j = 0; j < 8; ++j) {
        gp[j] = fmaf(W_ih[j], xv,
                 fmaf(W_hh[2*j], h0v,
                  fmaf(W_hh[2*j+1], h1v, b_ih[j] + b_hh[j])));
    }
    float i0 = sigmoid_f(gp[0]), i1 = sigmoid_f(gp[1]);
    float f0 = sigmoid_f(gp[2]), f1 = sigmoid_f(gp[3]);
    float g0 = tanh_f(gp[4]),    g1 = tanh_f(gp[5]);
    float o0 = sigmoid_f(gp[6]), o1 = sigmoid_f(gp[7]);
    float cn0 = fmaf(f0, c0v, i0 * g0);
    float cn1 = fmaf(f1, c1v, i1 * g1);
    hx = fmaxf(o0 * tanh_f(cn0), 0.0f);
    hy = fmaxf(o1 * tanh_f(cn1), 0.0f);
}

// Exact model evaluation (fallback path, rarely taken).
__device__ void full_eval(
    float xv, float h0v, float h1v, float c0v, float c1v,
    const float* __restrict__ W_ih, const float* __restrict__ W_hh,
    const float* __restrict__ b_ih, const float* __restrict__ b_hh,
    const float* __restrict__ W1,   const float* __restrict__ b1,
    const float* __restrict__ W2,   const float* __restrict__ b2,
    float* a)
{
    float hx, hy;
    lstm_part(xv, h0v, h1v, c0v, c1v, W_ih, W_hh, b_ih, b_hh, hx, hy);
    float a0 = b2[0], a1 = b2[1], a2 = b2[2], a3 = b2[3], a4 = b2[4];
#pragma unroll 2
    for (int j = 0; j < FC1; ++j) {
        float u = fmaf(W1[2*j], hx, fmaf(W1[2*j+1], hy, b1[j]));
        u = fmaxf(u, 0.0f);
        a0 = fmaf(W2[0*FC1 + j], u, a0);
        a1 = fmaf(W2[1*FC1 + j], u, a1);
        a2 = fmaf(W2[2*FC1 + j], u, a2);
        a3 = fmaf(W2[3*FC1 + j], u, a3);
        a4 = fmaf(W2[4*FC1 + j], u, a4);
    }
    a[0] = a0; a[1] = a1; a[2] = a2; a[3] = a3; a[4] = a4;
}

// LUT build: 32 lanes per entry, 4 FC1 neurons each, shfl-xor reduce.
__global__ __launch_bounds__(256) void build_lut_kernel(
    const float* __restrict__ W_ih, const float* __restrict__ W_hh,
    const float* __restrict__ b_ih, const float* __restrict__ b_hh,
    const float* __restrict__ W1,   const float* __restrict__ b1,
    const float* __restrict__ W2,   const float* __restrict__ b2)
{
    int tid = blockIdx.x * blockDim.x + threadIdx.x;
    int e = tid >> 5;
    int l = tid & 31;
    if (e > NT) return;

    float xv = XLO + (XHI - XLO) * ((float)e / (float)NT);
    float hx, hy;
    lstm_part(xv, 0.0f, 0.0f, 0.0f, 0.0f, W_ih, W_hh, b_ih, b_hh, hx, hy);

    float a0 = 0.f, a1 = 0.f, a2 = 0.f, a3 = 0.f, a4 = 0.f;
    int j0 = l * 4;
#pragma unroll
    for (int jj = 0; jj < 4; ++jj) {
        int j = j0 + jj;
        float u = fmaf(W1[2*j], hx, fmaf(W1[2*j+1], hy, b1[j]));
        u = fmaxf(u, 0.0f);
        a0 = fmaf(W2[0*FC1 + j], u, a0);
        a1 = fmaf(W2[1*FC1 + j], u, a1);
        a2 = fmaf(W2[2*FC1 + j], u, a2);
        a3 = fmaf(W2[3*FC1 + j], u, a3);
        a4 = fmaf(W2[4*FC1 + j], u, a4);
    }
#pragma unroll
    for (int m = 1; m < 32; m <<= 1) {
        a0 += __shfl_xor(a0, m);
        a1 += __shfl_xor(a1, m);
        a2 += __shfl_xor(a2, m);
        a3 += __shfl_xor(a3, m);
        a4 += __shfl_xor(a4, m);
    }
    if (l == 0) {
        g_A[e] = make_float4(a0 + b2[0], a1 + b2[1], a2 + b2[2], a3 + b2[3]);
        g_D[e] = a4 + b2[4];
    }
}

// Main: 4 samples/thread, 10.3 KB LUT in LDS, float4 I/O.
__global__ __launch_bounds__(256) void lstm_mlp_main(
    const float* __restrict__ x,
    const float* __restrict__ h0,
    const float* __restrict__ c0,
    const float* __restrict__ W_ih, const float* __restrict__ W_hh,
    const float* __restrict__ b_ih, const float* __restrict__ b_hh,
    const float* __restrict__ W1,   const float* __restrict__ b1,
    const float* __restrict__ W2,   const float* __restrict__ b2,
    float* __restrict__ out, int n)
{
    __shared__ float4 sA[NT + 1];
    __shared__ float  sD[NT + 1];
    int tid = threadIdx.x;
    int i0 = (blockIdx.x * 256 + tid) * 4;

    // Issue sample loads first so HBM latency hides under LUT staging.
    float4 xv = *reinterpret_cast<const float4*>(x + i0);
    float4 ha = *reinterpret_cast<const float4*>(h0 + 2 * (size_t)i0);
    float4 hb = *reinterpret_cast<const float4*>(h0 + 2 * (size_t)i0 + 4);
    float4 ca = *reinterpret_cast<const float4*>(c0 + 2 * (size_t)i0);
    float4 cb = *reinterpret_cast<const float4*>(c0 + 2 * (size_t)i0 + 4);

    // Stage the table (coalesced; 513 entries, 256 threads -> 2-3 iters).
    for (int idx = tid; idx <= NT; idx += 256) {
        sA[idx] = g_A[idx];
        sD[idx] = g_D[idx];
    }
    __syncthreads();

    float xs[4] = {xv.x, xv.y, xv.z, xv.w};
    float hs[8] = {ha.x, ha.y, ha.z, ha.w, hb.x, hb.y, hb.z, hb.w};
    float cs[8] = {ca.x, ca.y, ca.z, ca.w, cb.x, cb.y, cb.z, cb.w};
    float r[20];

#pragma unroll
    for (int s = 0; s < 4; ++s) {
        float xvs = xs[s];
        float h0v = hs[2*s], h1v = hs[2*s+1];
        float c0v = cs[2*s], c1v = cs[2*s+1];
        float* a = r + 5 * s;
        if (h0v == 0.0f && h1v == 0.0f && c0v == 0.0f && c1v == 0.0f &&
            xvs > XLO && xvs < XHI) {
            float t = (xvs - XLO) * SCALE;
            int k = (int)t;
            k = min(k, NT - 1);
            float fr = t - (float)k;
            float4 lo = sA[k];
            float4 hi = sA[k + 1];
            float dlo = sD[k];
            float dhi = sD[k + 1];
            a[0] = fmaf(fr, hi.x - lo.x, lo.x);
            a[1] = fmaf(fr, hi.y - lo.y, lo.y);
            a[2] = fmaf(fr, hi.z - lo.z, lo.z);
            a[3] = fmaf(fr, hi.w - lo.w, lo.w);
            a[4] = fmaf(fr, dhi - dlo, dlo);
        } else {
            full_eval(xvs, h0v, h1v, c0v, c1v,
                      W_ih, W_hh, b_ih, b_hh, W1, b1, W2, b2, a);
        }
    }

    float4* op = reinterpret_cast<float4*>(out + (size_t)i0 * 5);
    op[0] = make_float4(r[0],  r[1],  r[2],  r[3]);
    op[1] = make_float4(r[4],  r[5],  r[6],  r[7]);
    op[2] = make_float4(r[8],  r[9],  r[10], r[11]);
    op[3] = make_float4(r[12], r[13], r[14], r[15]);
    op[4] = make_float4(r[16], r[17], r[18], r[19]);
}

extern "C" void kernel_launch(void* const* d_in, const int* in_sizes, int n_in,
                              void* d_out, int out_size, void* d_ws, size_t ws_size,
                              hipStream_t stream) {
    const float* x    = (const float*)d_in[0];
    const float* h0   = (const float*)d_in[1];
    const float* c0   = (const float*)d_in[2];
    const float* W_ih = (const float*)d_in[3];
    const float* W_hh = (const float*)d_in[4];
    const float* b_ih = (const float*)d_in[5];
    const float* b_hh = (const float*)d_in[6];
    const float* W1   = (const float*)d_in[7];
    const float* b1   = (const float*)d_in[8];
    const float* W2   = (const float*)d_in[9];
    const float* b2   = (const float*)d_in[10];
    float* out = (float*)d_out;

    int n = in_sizes[0];  // B = 524288 (divisible by 1024)

    // 1) build F(x) table: (NT+1)*32 threads
    int bt = (NT + 1) * 32;
    build_lut_kernel<<<(bt + 255) / 256, 256, 0, stream>>>(
        W_ih, W_hh, b_ih, b_hh, W1, b1, W2, b2);

    // 2) main pass: 4 samples/thread
    int threads = n / 4;
    int grid = (threads + 255) / 256;
    lstm_mlp_main<<<grid, 256, 0, stream>>>(
        x, h0, c0, W_ih, W_hh, b_ih, b_hh, W1, b1, W2, b2, out, n);
}